// Round 6
// baseline (121.744 us; speedup 1.0000x reference)
//
#include <hip/hip_runtime.h>

typedef float f32x4 __attribute__((ext_vector_type(4)));

constexpr int B = 256, N = 512, T = 200, TM1 = 199;
constexpr int JPT = 4;                               // j's per thread
constexpr int SLOTS = 50;                            // ceil(199/4)
constexpr unsigned MAIN_THREADS = (unsigned)B * N * SLOTS;    // 6,553,600
constexpr unsigned MAIN_BLOCKS  = MAIN_THREADS / 256;         // 25,600 exact
constexpr unsigned ITEM_BLOCKS  = ((unsigned)B * TM1) / 256;  // 199 exact
constexpr float MIN_HL = 15.0f / (24.0f * 60.0f);
constexpr float MAX_HL = 274.0f;
constexpr float INV_SPD = 1.0f / 86400.0f;

__device__ __forceinline__ float hl_of(float s0, float s1, float s2,
                                       float th0, float th1, float th2) {
    float logit = fmaf(s0, th0, fmaf(s1, th1, s2 * th2));
    return fminf(fmaxf(exp2f(logit), MIN_HL), MAX_HL);
}

__device__ __forceinline__ float p_of(float hl, float dt_days) {
    // z = 2^(-dt/hl), sigmoid(z) = 1/(1+exp(-z)); hl in [MIN_HL,MAX_HL] -> rcp safe
    float z = exp2f(-dt_days * __builtin_amdgcn_rcpf(hl));
    return __builtin_amdgcn_rcpf(1.0f + __expf(-z));
}

__global__ __launch_bounds__(256) void hlr_fused(
    const float* __restrict__ x0,
    const float* __restrict__ t,
    const int*   __restrict__ items,
    const float* __restrict__ stats,
    const float* __restrict__ theta,
    float* __restrict__ x_pred,     // (B*N, T)
    float* __restrict__ x_item,     // (B, TM1)
    float* __restrict__ half_life)  // (B*N, TM1)
{
    const float th0 = theta[0], th1 = theta[1], th2 = theta[2];
    const unsigned bid = blockIdx.x;

    if (bid < MAIN_BLOCKS) {
        const unsigned idx  = bid * 256u + threadIdx.x;
        const unsigned row  = idx / SLOTS;           // b*N + n
        const unsigned slot = idx - row * SLOTS;
        const unsigned b    = row >> 9;              // N = 512
        const int j0 = slot * JPT;                   // 0,4,...,196

        // --- stats: 3 aligned 16B NT loads (row base 2400B; j0*12B, j0%4==0 -> 16B aligned)
        const f32x4* sp = reinterpret_cast<const f32x4*>(
            stats + (size_t)row * (T * 3) + (size_t)j0 * 3);
        const f32x4 sA = __builtin_nontemporal_load(sp);
        const f32x4 sB = __builtin_nontemporal_load(sp + 1);
        const f32x4 sC = __builtin_nontemporal_load(sp + 2);

        // --- t: t[j0..j0+4]; aligned f32x4 + guarded scalar
        const float* trow = t + (size_t)b * T;
        const f32x4 ta = *reinterpret_cast<const f32x4*>(trow + j0);
        const float t4 = (j0 + 4 < T) ? trow[j0 + 4] : 0.f;  // slot 49 doesn't use it

        // per-j triplets: j0:(A.x,A.y,A.z) j0+1:(A.w,B.x,B.y) j0+2:(B.z,B.w,C.x) j0+3:(C.y,C.z,C.w)
        const float hl0 = hl_of(sA.x, sA.y, sA.z, th0, th1, th2);
        const float hl1 = hl_of(sA.w, sB.x, sB.y, th0, th1, th2);
        const float hl2 = hl_of(sB.z, sB.w, sC.x, th0, th1, th2);
        const float hl3 = hl_of(sC.y, sC.z, sC.w, th0, th1, th2);

        const float p0 = p_of(hl0, (ta.y - ta.x) * INV_SPD);
        const float p1 = p_of(hl1, (ta.z - ta.y) * INV_SPD);
        const float p2 = p_of(hl2, (ta.w - ta.z) * INV_SPD);
        const float p3 = p_of(hl3, (t4   - ta.w) * INV_SPD);

        float* xp = x_pred    + (size_t)row * T;
        float* hp = half_life + (size_t)row * TM1;

        if (slot == 0) xp[0] = x0[row];

        xp[j0 + 1] = p0;  hp[j0]     = hl0;
        xp[j0 + 2] = p1;  hp[j0 + 1] = hl1;
        xp[j0 + 3] = p2;  hp[j0 + 2] = hl2;
        if (j0 + 3 < TM1) { xp[j0 + 4] = p3; hp[j0 + 3] = hl3; }
    } else {
        // --- x_item_pred: gather + recompute (50,944 threads)
        const int i = (int)(bid - MAIN_BLOCKS) * 256 + (int)threadIdx.x;  // < B*TM1
        const int b = i / TM1;
        const int j = i - b * TM1;
        const int n = items[(size_t)b * T + j + 1];

        const float* sg = stats + ((size_t)((size_t)b * N + n) * T + j) * 3;
        float s0, s1, s2;
        __builtin_memcpy(&s0, sg,     4);
        __builtin_memcpy(&s1, sg + 1, 4);
        __builtin_memcpy(&s2, sg + 2, 4);
        const float hl = hl_of(s0, s1, s2, th0, th1, th2);
        const float dt = (t[(size_t)b * T + j + 1] - t[(size_t)b * T + j]) * INV_SPD;
        x_item[i] = p_of(hl, dt);
    }
}

extern "C" void kernel_launch(void* const* d_in, const int* in_sizes, int n_in,
                              void* d_out, int out_size, void* d_ws, size_t ws_size,
                              hipStream_t stream) {
    const float* x0    = (const float*)d_in[0];
    const float* t     = (const float*)d_in[1];
    const int*   items = (const int*)d_in[2];
    const float* stats = (const float*)d_in[3];
    const float* theta = (const float*)d_in[4];

    float* out = (float*)d_out;
    float* x_pred    = out;                                        // B*N*T
    float* x_item    = out + (size_t)B * N * T;                    // B*TM1
    float* half_life = out + (size_t)B * N * T + (size_t)B * TM1;  // B*N*TM1

    hlr_fused<<<MAIN_BLOCKS + ITEM_BLOCKS, 256, 0, stream>>>(
        x0, t, items, stats, theta, x_pred, x_item, half_life);
}

// Round 7
// 112.768 us; speedup vs baseline: 1.0796x; 1.0796x over previous
//
#include <hip/hip_runtime.h>

typedef float f32x4 __attribute__((ext_vector_type(4)));

constexpr int B = 256, N = 512, T = 200, TM1 = 199;
constexpr unsigned ROWS = (unsigned)B * N;                   // 131072 main blocks (1 row each)
constexpr unsigned ITEM_BLOCKS = ((unsigned)B * TM1) / 256;  // 199 exact
constexpr float MIN_HL = 15.0f / (24.0f * 60.0f);
constexpr float MAX_HL = 274.0f;
constexpr float INV_SPD = 1.0f / 86400.0f;

__device__ __forceinline__ float hl_of(float s0, float s1, float s2,
                                       float th0, float th1, float th2) {
    float logit = fmaf(s0, th0, fmaf(s1, th1, s2 * th2));
    return fminf(fmaxf(exp2f(logit), MIN_HL), MAX_HL);
}

__device__ __forceinline__ float p_of(float hl, float dt_days) {
    float z = exp2f(-dt_days / hl);
    return 1.0f / (1.0f + __expf(-z));   // sigmoid(z), z in (0,1]
}

__global__ __launch_bounds__(256) void hlr_fused(
    const float* __restrict__ x0,
    const float* __restrict__ t,
    const int*   __restrict__ items,
    const float* __restrict__ stats,
    const float* __restrict__ theta,
    float* __restrict__ x_pred,     // (B*N, T)
    float* __restrict__ x_item,     // (B, TM1)
    float* __restrict__ half_life)  // (B*N, TM1) flat
{
    const float th0 = theta[0], th1 = theta[1], th2 = theta[2];
    const unsigned bid = blockIdx.x;

    if (bid < ROWS) {
        __shared__ float s_p[T];      // staged x_pred row (x0 at 0, p at 1..199)
        __shared__ float s_h[T];      // staged half_life row (0..198)

        const unsigned row = bid;
        const unsigned b   = row >> 9;            // N = 512
        const int j = (int)threadIdx.x;

        if (j < TM1) {
            // stats[row, j, 0:3] — 12B lane stride, fully coalesced dword loads
            const float* sg = stats + (size_t)row * (T * 3) + (size_t)j * 3;
            float s0, s1, s2;
            __builtin_memcpy(&s0, sg,     4);
            __builtin_memcpy(&s1, sg + 1, 4);
            __builtin_memcpy(&s2, sg + 2, 4);

            const float tj  = t[(size_t)b * T + j];
            const float tj1 = t[(size_t)b * T + j + 1];

            const float hl = hl_of(s0, s1, s2, th0, th1, th2);
            const float p  = p_of(hl, (tj1 - tj) * INV_SPD);

            s_p[j + 1] = p;
            s_h[j]     = hl;
            if (j == 0) s_p[0] = x0[row];
        }
        __syncthreads();

        // --- x_pred row: 800B, 16B-aligned -> 50 packed nt f32x4 (full-line coverage)
        float* xp = x_pred + (size_t)row * T;
        const unsigned k = threadIdx.x;
        if (k < 50) {
            f32x4 v = { s_p[4*k], s_p[4*k+1], s_p[4*k+2], s_p[4*k+3] };
            __builtin_nontemporal_store(v, reinterpret_cast<f32x4*>(xp) + k);
        }

        // --- half_life: flat base = row*199 (odd stride) -> lead scalars / 49 f32x4 / tail
        const size_t base = (size_t)row * TM1;
        const unsigned lead = (unsigned)((4 - (base & 3)) & 3);
        if (k < lead)
            __builtin_nontemporal_store(s_h[k], half_life + base + k);
        const unsigned nvec = (TM1 - lead) >> 2;      // always 49
        if (k < nvec) {
            const unsigned o = lead + 4*k;
            f32x4 v = { s_h[o], s_h[o+1], s_h[o+2], s_h[o+3] };
            __builtin_nontemporal_store(
                v, reinterpret_cast<f32x4*>(half_life + base + lead) + k);
        }
        const unsigned done = lead + 4*nvec;
        const unsigned tail = TM1 - done;             // 0..3
        if (k < tail)
            __builtin_nontemporal_store(s_h[done + k], half_life + base + done + k);
    } else {
        // --- x_item_pred: gather + recompute (50,944 threads)
        const int i = (int)(bid - ROWS) * 256 + (int)threadIdx.x;  // < B*TM1
        const int b = i / TM1;
        const int j = i - b * TM1;
        const int n = items[(size_t)b * T + j + 1];

        const float* sg = stats + ((size_t)((size_t)b * N + n) * T + j) * 3;
        float s0, s1, s2;
        __builtin_memcpy(&s0, sg,     4);
        __builtin_memcpy(&s1, sg + 1, 4);
        __builtin_memcpy(&s2, sg + 2, 4);
        const float hl = hl_of(s0, s1, s2, th0, th1, th2);
        const float dt = (t[(size_t)b * T + j + 1] - t[(size_t)b * T + j]) * INV_SPD;
        __builtin_nontemporal_store(p_of(hl, dt), x_item + i);
    }
}

extern "C" void kernel_launch(void* const* d_in, const int* in_sizes, int n_in,
                              void* d_out, int out_size, void* d_ws, size_t ws_size,
                              hipStream_t stream) {
    const float* x0    = (const float*)d_in[0];
    const float* t     = (const float*)d_in[1];
    const int*   items = (const int*)d_in[2];
    const float* stats = (const float*)d_in[3];
    const float* theta = (const float*)d_in[4];

    float* out = (float*)d_out;
    float* x_pred    = out;                                        // B*N*T
    float* x_item    = out + (size_t)B * N * T;                    // B*TM1
    float* half_life = out + (size_t)B * N * T + (size_t)B * TM1;  // B*N*TM1

    hlr_fused<<<ROWS + ITEM_BLOCKS, 256, 0, stream>>>(
        x0, t, items, stats, theta, x_pred, x_item, half_life);
}

// Round 8
// 100.910 us; speedup vs baseline: 1.2065x; 1.1175x over previous
//
#include <hip/hip_runtime.h>

typedef float f32x4 __attribute__((ext_vector_type(4)));

constexpr int B = 256, N = 512, T = 200, TM1 = 199;
constexpr int JPT = 4;                               // j's per thread (best measured)
constexpr int SLOTS = 50;                            // ceil(199/4)
constexpr unsigned MAIN_THREADS = (unsigned)B * N * SLOTS;    // 6,553,600
constexpr unsigned MAIN_BLOCKS  = MAIN_THREADS / 256;         // 25,600 exact
constexpr unsigned ITEM_BLOCKS  = ((unsigned)B * TM1) / 256;  // 199 exact
constexpr float MIN_HL = 15.0f / (24.0f * 60.0f);
constexpr float MAX_HL = 274.0f;
constexpr float INV_SPD = 1.0f / 86400.0f;
constexpr float LOG2E = 1.44269504088896340736f;

__device__ __forceinline__ float hl_of(float s0, float s1, float s2,
                                       float th0, float th1, float th2) {
    float logit = fmaf(s0, th0, fmaf(s1, th1, s2 * th2));
    return fminf(fmaxf(exp2f(logit), MIN_HL), MAX_HL);
}

__device__ __forceinline__ float p_of(float hl, float dt_days) {
    // z = 2^(-dt/hl) in (0,1]; sigmoid(z) = 1/(1 + 2^(-z*log2e)); hl clamped -> rcp safe
    float z = exp2f(-dt_days * __builtin_amdgcn_rcpf(hl));
    return __builtin_amdgcn_rcpf(1.0f + exp2f(-LOG2E * z));
}

__global__ __launch_bounds__(256) void hlr_fused(
    const float* __restrict__ x0,
    const float* __restrict__ t,
    const int*   __restrict__ items,
    const float* __restrict__ stats,
    const float* __restrict__ theta,
    float* __restrict__ x_pred,     // (B*N, T)
    float* __restrict__ x_item,     // (B, TM1)
    float* __restrict__ half_life)  // (B*N, TM1)
{
    const float th0 = theta[0], th1 = theta[1], th2 = theta[2];
    const unsigned bid = blockIdx.x;

    if (bid < MAIN_BLOCKS) {
        const unsigned idx  = bid * 256u + threadIdx.x;
        const unsigned row  = idx / SLOTS;           // b*N + n (magic-mul)
        const unsigned slot = idx - row * SLOTS;
        const unsigned b    = row >> 9;              // N = 512
        const int j0 = slot * JPT;                   // 0,4,...,196

        // --- stats: 3 aligned 16B loads (row base 2400B; j0*12B, j0%4==0 -> 16B aligned)
        const f32x4* sp = reinterpret_cast<const f32x4*>(
            stats + (size_t)row * (T * 3) + (size_t)j0 * 3);
        const f32x4 sA = sp[0];
        const f32x4 sB = sp[1];
        const f32x4 sC = sp[2];

        // --- t: t[j0..j0+4]; aligned f32x4 + guarded scalar
        const float* trow = t + (size_t)b * T;
        const f32x4 ta = *reinterpret_cast<const f32x4*>(trow + j0);
        const float t4 = (j0 + 4 < T) ? trow[j0 + 4] : 0.f;  // slot 49 doesn't use it

        // per-j triplets: j0:(A.x,A.y,A.z) j0+1:(A.w,B.x,B.y) j0+2:(B.z,B.w,C.x) j0+3:(C.y,C.z,C.w)
        const float hl0 = hl_of(sA.x, sA.y, sA.z, th0, th1, th2);
        const float hl1 = hl_of(sA.w, sB.x, sB.y, th0, th1, th2);
        const float hl2 = hl_of(sB.z, sB.w, sC.x, th0, th1, th2);
        const float hl3 = hl_of(sC.y, sC.z, sC.w, th0, th1, th2);

        const float p0 = p_of(hl0, (ta.y - ta.x) * INV_SPD);
        const float p1 = p_of(hl1, (ta.z - ta.y) * INV_SPD);
        const float p2 = p_of(hl2, (ta.w - ta.z) * INV_SPD);
        const float p3 = p_of(hl3, (t4   - ta.w) * INV_SPD);

        float* xp = x_pred    + (size_t)row * T;
        float* hp = half_life + (size_t)row * TM1;

        if (slot == 0) xp[0] = x0[row];

        xp[j0 + 1] = p0;  hp[j0]     = hl0;
        xp[j0 + 2] = p1;  hp[j0 + 1] = hl1;
        xp[j0 + 3] = p2;  hp[j0 + 2] = hl2;
        if (j0 + 3 < TM1) { xp[j0 + 4] = p3; hp[j0 + 3] = hl3; }
    } else {
        // --- x_item_pred: gather + recompute (50,944 threads)
        const int i = (int)(bid - MAIN_BLOCKS) * 256 + (int)threadIdx.x;  // < B*TM1
        const int b = i / TM1;
        const int j = i - b * TM1;
        const int n = items[(size_t)b * T + j + 1];

        const float* sg = stats + ((size_t)((size_t)b * N + n) * T + j) * 3;
        float s0, s1, s2;
        __builtin_memcpy(&s0, sg,     4);
        __builtin_memcpy(&s1, sg + 1, 4);
        __builtin_memcpy(&s2, sg + 2, 4);
        const float hl = hl_of(s0, s1, s2, th0, th1, th2);
        const float dt = (t[(size_t)b * T + j + 1] - t[(size_t)b * T + j]) * INV_SPD;
        x_item[i] = p_of(hl, dt);
    }
}

extern "C" void kernel_launch(void* const* d_in, const int* in_sizes, int n_in,
                              void* d_out, int out_size, void* d_ws, size_t ws_size,
                              hipStream_t stream) {
    const float* x0    = (const float*)d_in[0];
    const float* t     = (const float*)d_in[1];
    const int*   items = (const int*)d_in[2];
    const float* stats = (const float*)d_in[3];
    const float* theta = (const float*)d_in[4];

    float* out = (float*)d_out;
    float* x_pred    = out;                                        // B*N*T
    float* x_item    = out + (size_t)B * N * T;                    // B*TM1
    float* half_life = out + (size_t)B * N * T + (size_t)B * TM1;  // B*N*TM1

    hlr_fused<<<MAIN_BLOCKS + ITEM_BLOCKS, 256, 0, stream>>>(
        x0, t, items, stats, theta, x_pred, x_item, half_life);
}